// Round 10
// baseline (261.988 us; speedup 1.0000x reference)
//
#include <hip/hip_runtime.h>

typedef __attribute__((ext_vector_type(8))) short bf16x8;
typedef __attribute__((ext_vector_type(4))) short bf16x4;
typedef __attribute__((ext_vector_type(4))) float f32x4;

#define L2E 1.44269504088896340736f
#define QSCL 0.18033688011112042f   // 0.125 * log2(e)

__device__ inline unsigned short f2bf(float f) {
  union { float f; unsigned int u; } x; x.f = f;
  return (unsigned short)((x.u + 0x8000u) >> 16);
}
__device__ inline unsigned int f2bf2(float a, float b) {
  union { float f; unsigned int u; } xa, xb;
  xa.f = a; xb.f = b;
  return ((xa.u + 0x8000u) >> 16) | (((xb.u + 0x8000u) & 0xFFFF0000u));
}
// HW packed f32->bf16x2 (gfx950 v_cvt_pk_bf16_f32), compile-safe fallback.
__device__ inline unsigned int pk_bf16(float a, float b) {
#if __has_builtin(__builtin_amdgcn_cvt_pk_bf16_f32)
  typedef __attribute__((ext_vector_type(2))) __bf16 bfv2;
  union { bfv2 v; unsigned int u; } x;
  x.v = __builtin_amdgcn_cvt_pk_bf16_f32(a, b);
  return x.u;
#else
  return f2bf2(a, b);
#endif
}

__device__ inline void gl_lds16(const void* g, void* l) {
  __builtin_amdgcn_global_load_lds((const __attribute__((address_space(1))) void*)g,
                                   (__attribute__((address_space(3))) void*)l,
                                   16, 0, 0);
}

// Explicit LDS-DMA drain before each barrier: the compiler's alias-based
// vmcnt tracking dropped the wait in R4 (warm-replay race). Keep always.
__device__ inline void vm_drain() {
  asm volatile("s_waitcnt vmcnt(0)" ::: "memory");
}

// ---------------- fused cast fp32 -> bf16 (x, W_qkv, W_out) ----------------
#define N4_X  2097152   // 8192*1024/4
#define N4_WQ 786432    // 3072*1024/4
#define N4_WO 262144    // 1024*1024/4
__global__ void cast3_kernel(const float* __restrict__ x,
                             const float* __restrict__ wq,
                             const float* __restrict__ wo,
                             unsigned short* __restrict__ xb,
                             unsigned short* __restrict__ wqb,
                             unsigned short* __restrict__ wob) {
  int i = blockIdx.x * blockDim.x + threadIdx.x;
  int st = gridDim.x * blockDim.x;
  for (; i < N4_X + N4_WQ + N4_WO; i += st) {
    const float* src; unsigned short* dst; int j;
    if (i < N4_X)            { src = x;  dst = xb;  j = i; }
    else if (i < N4_X + N4_WQ){ src = wq; dst = wqb; j = i - N4_X; }
    else                     { src = wo; dst = wob; j = i - N4_X - N4_WQ; }
    float4 v = reinterpret_cast<const float4*>(src)[j];
    ushort4 o;
    o.x = f2bf(v.x); o.y = f2bf(v.y); o.z = f2bf(v.z); o.w = f2bf(v.w);
    reinterpret_cast<ushort4*>(dst)[j] = o;
  }
}

// ---------------- QKV GEMM: [8192,1024] x [3072,1024]^T ----------------
// Compile-time MODE bodies (R6 lesson: runtime branch inside the MFMA K-loop
// spills acc[4][4] to scratch). R10: paired-tile persistent blocks — grid
// 12x64 = 768 blocks = exactly 3/CU all co-resident (the 24x64=1536-block grid
// at 4/CU ran 1.5 occupancy passes -> ~75% util tail loss). Each block does
// tiles (tn, tn+12) at the same tm. Inter-tile LDS safety: tile1's last iter
// reads buf1, tile2's prologue writes buf0 only; tile2's first-iter barrier
// orders the rest.
template <int MODE>
__device__ __forceinline__ void gemm_qkv_body(
    unsigned short* __restrict__ sA,   // [2][128*32] flattened
    unsigned short* __restrict__ sB,
    const unsigned short* __restrict__ A,
    const unsigned short* __restrict__ Bm,
    unsigned short* __restrict__ qo,
    unsigned short* __restrict__ ko,
    unsigned short* __restrict__ vo,
    int tn) {
  const int K = 1024;
  const int tid = threadIdx.x;
  const int w = tid >> 6, lane = tid & 63;
  const int l15 = lane & 15, quad = lane >> 4;
  const int wm = (w >> 1) * 64, wn = (w & 1) * 64;
  const int tm = blockIdx.y;

  const unsigned short* Ab = A + (size_t)(tm * 128) * K;
  const unsigned short* Bb = Bm + (size_t)(tn * 128) * K;

  const int srow = w * 32 + (lane >> 2);
  const int scol = (((lane & 3) ^ ((lane >> 3) & 3))) * 8;   // swizzled content chunk
  const int rsw = (l15 >> 1) & 3;                            // read-side swizzle key

  const f32x4 fz = {0.f, 0.f, 0.f, 0.f};
  f32x4 acc[4][4];
#pragma unroll
  for (int i = 0; i < 4; i++)
#pragma unroll
    for (int j = 0; j < 4; j++) acc[i][j] = fz;

  gl_lds16(Ab + (size_t)srow * K + scol,        &sA[(w * 32) * 32]);
  gl_lds16(Ab + (size_t)(srow + 16) * K + scol, &sA[(w * 32 + 16) * 32]);
  gl_lds16(Bb + (size_t)srow * K + scol,        &sB[(w * 32) * 32]);
  gl_lds16(Bb + (size_t)(srow + 16) * K + scol, &sB[(w * 32 + 16) * 32]);

  int buf = 0;
  for (int k0 = 0; k0 < K; k0 += 32) {
    vm_drain();
    __syncthreads();
    if (k0 + 32 < K) {
      int nb = buf ^ 1, kn = k0 + 32;
      gl_lds16(Ab + (size_t)srow * K + kn + scol,        &sA[nb * 4096 + (w * 32) * 32]);
      gl_lds16(Ab + (size_t)(srow + 16) * K + kn + scol, &sA[nb * 4096 + (w * 32 + 16) * 32]);
      gl_lds16(Bb + (size_t)srow * K + kn + scol,        &sB[nb * 4096 + (w * 32) * 32]);
      gl_lds16(Bb + (size_t)(srow + 16) * K + kn + scol, &sB[nb * 4096 + (w * 32 + 16) * 32]);
    }
    bf16x8 af[4], bfr[4];
#pragma unroll
    for (int mt = 0; mt < 4; mt++)
      af[mt] = *(const bf16x8*)&sA[buf * 4096 + (wm + mt * 16 + l15) * 32 + ((quad ^ rsw) << 3)];
#pragma unroll
    for (int nt = 0; nt < 4; nt++)
      bfr[nt] = *(const bf16x8*)&sB[buf * 4096 + (wn + nt * 16 + l15) * 32 + ((quad ^ rsw) << 3)];
#pragma unroll
    for (int mt = 0; mt < 4; mt++)
#pragma unroll
      for (int nt = 0; nt < 4; nt++) {
        if (MODE == 0)
          acc[mt][nt] = __builtin_amdgcn_mfma_f32_16x16x32_bf16(bfr[nt], af[mt], acc[mt][nt], 0, 0, 0);
        else
          acc[mt][nt] = __builtin_amdgcn_mfma_f32_16x16x32_bf16(af[mt], bfr[nt], acc[mt][nt], 0, 0, 0);
      }
    buf ^= 1;
  }

  const int m0 = tm * 128;
  const int bb = m0 >> 10, n0 = m0 & 1023;
  const int cbase = (tn * 128) & 1023;

  if (MODE == 0) {
    const int which = tn >> 3;                 // 0:q 1:k
    const float scl = (which == 0) ? QSCL : 1.0f;
    unsigned short* dst = (which == 0) ? qo : ko;
#pragma unroll
    for (int mt = 0; mt < 4; mt++) {
      int tok = n0 + wm + mt * 16 + l15;
#pragma unroll
      for (int nt = 0; nt < 4; nt++) {
        int c = cbase + wn + nt * 16 + quad * 4;
        int hh = c >> 6, d0 = c & 63;
        uint2 val;
        val.x = f2bf2(acc[mt][nt][0] * scl, acc[mt][nt][1] * scl);
        val.y = f2bf2(acc[mt][nt][2] * scl, acc[mt][nt][3] * scl);
        *(uint2*)&dst[(((size_t)bb * 16 + hh) * 1024 + tok) * 64 + d0] = val;
      }
    }
  } else {
#pragma unroll
    for (int mt = 0; mt < 4; mt++) {
      int tok = n0 + wm + mt * 16 + quad * 4;
#pragma unroll
      for (int nt = 0; nt < 4; nt++) {
        int c = cbase + wn + nt * 16 + l15;
        int hh = c >> 6, dd = c & 63;
        uint2 val;
        val.x = f2bf2(acc[mt][nt][0], acc[mt][nt][1]);
        val.y = f2bf2(acc[mt][nt][2], acc[mt][nt][3]);
        *(uint2*)&vo[(((size_t)bb * 16 + hh) * 64 + dd) * 1024 + tok] = val;
      }
    }
  }
}

__global__ __launch_bounds__(256, 4) void gemm_qkv(
    const unsigned short* __restrict__ A,
    const unsigned short* __restrict__ Bm,
    unsigned short* __restrict__ qo,
    unsigned short* __restrict__ ko,
    unsigned short* __restrict__ vo) {
  __shared__ unsigned short sA[2][128 * 32];
  __shared__ unsigned short sB[2][128 * 32];
  const int bx = blockIdx.x;                  // 0..11
  gemm_qkv_body<0>(&sA[0][0], &sB[0][0], A, Bm, qo, ko, vo, bx);
  if (bx < 4) gemm_qkv_body<0>(&sA[0][0], &sB[0][0], A, Bm, qo, ko, vo, bx + 12);
  else        gemm_qkv_body<1>(&sA[0][0], &sB[0][0], A, Bm, qo, ko, vo, bx + 12);
}

// ---------------- flash attention: S^T, register PV, reflected-bias, MFMA rsum ----
// qb=4: each wave covers 64 q-rows (block 256, grid 512). K/V LDS fragment
// reads are qb-independent -> per-CU K/V LDS traffic halves vs qb=2.
// Bias row index stays wave-uniform per qb: qi = qt*8 + w*2 + (qb>>1).
__global__ __launch_bounds__(256, 2) void attn_kernel(
    const unsigned short* __restrict__ Q,
    const unsigned short* __restrict__ Kg,
    const unsigned short* __restrict__ Vt,
    const float* __restrict__ biases,
    unsigned short* __restrict__ Og) {
  __shared__ unsigned short sK[2][64 * 64];
  __shared__ unsigned short sV[2][64 * 64];   // [d][kv], 16B-chunk XOR-swizzled
  __shared__ float sBias2[32 * 63];           // reflected: [di][31 + (qj-kvj)]

  const int bx = blockIdx.x;
  const int bh = bx & 127, qt = bx >> 7;      // qt 0..3; same bh -> same XCD
  const int h = bh & 15, b = bh >> 4;
  const int tid = threadIdx.x, w = tid >> 6, lane = tid & 63;
  const int l15 = lane & 15, quad = lane >> 4;

  const size_t bhs = (size_t)(b * 16 + h);
  const unsigned short* qbase = Q + (bhs * 1024 + (size_t)qt * 256) * 64;
  const unsigned short* kbase = Kg + bhs * 1024 * 64;
  const unsigned short* vbase = Vt + bhs * 64 * 1024;

  for (int t = tid; t < 2048; t += 256) {
    int d = t >> 6, u = t & 63;
    if (u < 63) {
      int dj = u - 31; dj = dj < 0 ? -dj : dj;
      sBias2[d * 63 + u] = biases[h * 1024 + d * 32 + dj] * L2E;
    }
  }

  const int sr0 = w * 16 + (lane >> 3);
  const int sc8 = lane & 7;
  const int sw0 = sc8 ^ (lane >> 3);

  gl_lds16(kbase + (size_t)sr0 * 64 + sw0 * 8,        &sK[0][(w * 16) * 64]);
  gl_lds16(kbase + (size_t)(sr0 + 8) * 64 + sw0 * 8,  &sK[0][(w * 16 + 8) * 64]);
  gl_lds16(vbase + (size_t)sr0 * 1024 + sw0 * 8,      &sV[0][(w * 16) * 64]);
  gl_lds16(vbase + (size_t)(sr0 + 8) * 1024 + sw0 * 8,&sV[0][(w * 16 + 8) * 64]);

  bf16x8 qf[4][2];
#pragma unroll
  for (int qb = 0; qb < 4; qb++)
#pragma unroll
    for (int kd = 0; kd < 2; kd++)
      qf[qb][kd] = *(const bf16x8*)(qbase + (w * 64 + qb * 16 + l15) * 64 + kd * 32 + quad * 8);

  const int qg0 = qt * 256 + w * 64;
  const int qtw = __builtin_amdgcn_readfirstlane(qt * 8 + w * 2);
  // signed column offset (table is reflected): depends only on (qb&1, kp)
  int cc2[2][2];
#pragma unroll
  for (int qh = 0; qh < 2; qh++)
#pragma unroll
    for (int kp = 0; kp < 2; kp++)
      cc2[qh][kp] = qh * 16 + l15 - kp * 16 - quad * 4;

  const f32x4 fz = {0.f, 0.f, 0.f, 0.f};
  f32x4 of[4][4], osum[4];
#pragma unroll
  for (int i = 0; i < 4; i++) {
    osum[i] = fz;
#pragma unroll
    for (int j = 0; j < 4; j++) of[i][j] = fz;
  }
  const bf16x4 vones = {(short)0x3F80, (short)0x3F80, (short)0x3F80, (short)0x3F80};

  int buf = 0;
  for (int j0 = 0; j0 < 1024; j0 += 64) {
    vm_drain();
    __syncthreads();
    if (j0 + 64 < 1024) {
      int nb = buf ^ 1, jn = j0 + 64;
      gl_lds16(kbase + (size_t)(jn + sr0) * 64 + sw0 * 8,       &sK[nb][(w * 16) * 64]);
      gl_lds16(kbase + (size_t)(jn + sr0 + 8) * 64 + sw0 * 8,   &sK[nb][(w * 16 + 8) * 64]);
      gl_lds16(vbase + (size_t)sr0 * 1024 + jn + sw0 * 8,       &sV[nb][(w * 16) * 64]);
      gl_lds16(vbase + (size_t)(sr0 + 8) * 1024 + jn + sw0 * 8, &sV[nb][(w * 16 + 8) * 64]);
    }
    const unsigned short* K_ = sK[buf];
    const unsigned short* V_ = sV[buf];
    const int j5 = j0 >> 5;
    const int dh = qtw - j5;                  // qi(qb) = qtw + (qb>>1)
    const float* b0 = sBias2 + abs(dh) * 63 + 31;       // (qb>>1) == (kvb>>1)
    const float* bM = sBias2 + abs(dh - 1) * 63 + 31;   // qb<2, kvb>=2
    const float* bP = sBias2 + abs(dh + 1) * 63 + 31;   // qb>=2, kvb<2

#pragma unroll
    for (int kvb = 0; kvb < 4; kvb++) {
      bf16x8 kf0 = *(const bf16x8*)&K_[(kvb * 16 + l15) * 64 + ((quad ^ (l15 & 7)) << 3)];
      bf16x8 kf1 = *(const bf16x8*)&K_[(kvb * 16 + l15) * 64 + (((4 + quad) ^ (l15 & 7)) << 3)];
      bf16x4 vf[4];
#pragma unroll
      for (int nt = 0; nt < 4; nt++) {
        int d = nt * 16 + l15;
        vf[nt] = *(const bf16x4*)&V_[d * 64 + (((kvb * 2 + (quad >> 1)) ^ (l15 & 7)) << 3) + (quad & 1) * 4];
      }
      const int kp = kvb & 1;
#pragma unroll
      for (int qb = 0; qb < 4; qb++) {
        f32x4 s4 = __builtin_amdgcn_mfma_f32_16x16x32_bf16(kf0, qf[qb][0], fz, 0, 0, 0);
        s4 = __builtin_amdgcn_mfma_f32_16x16x32_bf16(kf1, qf[qb][1], s4, 0, 0, 0);
        const float* bp = (qb < 2) ? ((kvb < 2) ? b0 : bM)
                                   : ((kvb < 2) ? bP : b0);
        const float* bq = bp + cc2[qb & 1][kp];   // bq[-r] = bias for kv=kvjb+r
        float p0 = __builtin_amdgcn_exp2f(s4.x + bq[0]);
        float p1 = __builtin_amdgcn_exp2f(s4.y + bq[-1]);
        float p2 = __builtin_amdgcn_exp2f(s4.z + bq[-2]);
        float p3 = __builtin_amdgcn_exp2f(s4.w + bq[-3]);
        union { unsigned int u[2]; bf16x4 v; } pk;
        pk.u[0] = pk_bf16(p0, p1);
        pk.u[1] = pk_bf16(p2, p3);
#pragma unroll
        for (int nt = 0; nt < 4; nt++)
          of[qb][nt] = __builtin_amdgcn_mfma_f32_16x16x16bf16_1k(pk.v, vf[nt], of[qb][nt], 0, 0, 0);
        osum[qb] = __builtin_amdgcn_mfma_f32_16x16x16bf16_1k(pk.v, vones, osum[qb], 0, 0, 0);
      }
    }
    buf ^= 1;
  }

  const int kvq = quad * 4;
#pragma unroll
  for (int qb = 0; qb < 4; qb++)
#pragma unroll
    for (int r = 0; r < 4; r++) {
      float inv = __builtin_amdgcn_rcpf(osum[qb][r]);   // same C-layout row as of
      int n = qg0 + qb * 16 + kvq + r;
      size_t orow = ((size_t)b * 1024 + n) * 1024 + h * 64;
#pragma unroll
      for (int nt = 0; nt < 4; nt++)
        Og[orow + nt * 16 + l15] = f2bf(of[qb][nt][r] * inv);
    }
}

// ---------------- out-proj GEMM: [8192,1024] x [1024,1024]^T + b ----------------
__global__ __launch_bounds__(256, 4) void gemm_out_k(
    const unsigned short* __restrict__ A,
    const unsigned short* __restrict__ Bm,
    const float* __restrict__ bias,
    float* __restrict__ out) {
  __shared__ unsigned short sA[2][128 * 32];
  __shared__ unsigned short sB[2][128 * 32];
  const int K = 1024;
  const int tid = threadIdx.x;
  const int w = tid >> 6, lane = tid & 63;
  const int l15 = lane & 15, quad = lane >> 4;
  const int wm = (w >> 1) * 64, wn = (w & 1) * 64;
  const int tm = blockIdx.y, tn = blockIdx.x;

  const unsigned short* Ab = A + (size_t)(tm * 128) * K;
  const unsigned short* Bb = Bm + (size_t)(tn * 128) * K;

  const int srow = w * 32 + (lane >> 2);
  const int scol = (((lane & 3) ^ ((lane >> 3) & 3))) * 8;
  const int rsw = (l15 >> 1) & 3;

  const f32x4 fz = {0.f, 0.f, 0.f, 0.f};
  f32x4 acc[4][4];
#pragma unroll
  for (int i = 0; i < 4; i++)
#pragma unroll
    for (int j = 0; j < 4; j++) acc[i][j] = fz;

  gl_lds16(Ab + (size_t)srow * K + scol,        &sA[0][(w * 32) * 32]);
  gl_lds16(Ab + (size_t)(srow + 16) * K + scol, &sA[0][(w * 32 + 16) * 32]);
  gl_lds16(Bb + (size_t)srow * K + scol,        &sB[0][(w * 32) * 32]);
  gl_lds16(Bb + (size_t)(srow + 16) * K + scol, &sB[0][(w * 32 + 16) * 32]);

  int buf = 0;
  for (int k0 = 0; k0 < K; k0 += 32) {
    vm_drain();
    __syncthreads();
    if (k0 + 32 < K) {
      int nb = buf ^ 1, kn = k0 + 32;
      gl_lds16(Ab + (size_t)srow * K + kn + scol,        &sA[nb][(w * 32) * 32]);
      gl_lds16(Ab + (size_t)(srow + 16) * K + kn + scol, &sA[nb][(w * 32 + 16) * 32]);
      gl_lds16(Bb + (size_t)srow * K + kn + scol,        &sB[nb][(w * 32) * 32]);
      gl_lds16(Bb + (size_t)(srow + 16) * K + kn + scol, &sB[nb][(w * 32 + 16) * 32]);
    }
    bf16x8 af[4], bfr[4];
#pragma unroll
    for (int mt = 0; mt < 4; mt++)
      af[mt] = *(const bf16x8*)&sA[buf][(wm + mt * 16 + l15) * 32 + ((quad ^ rsw) << 3)];
#pragma unroll
    for (int nt = 0; nt < 4; nt++)
      bfr[nt] = *(const bf16x8*)&sB[buf][(wn + nt * 16 + l15) * 32 + ((quad ^ rsw) << 3)];
#pragma unroll
    for (int mt = 0; mt < 4; mt++)
#pragma unroll
      for (int nt = 0; nt < 4; nt++)
        acc[mt][nt] = __builtin_amdgcn_mfma_f32_16x16x32_bf16(af[mt], bfr[nt], acc[mt][nt], 0, 0, 0);
    buf ^= 1;
  }

  const int m0 = tm * 128 + wm, c0 = tn * 128 + wn;
#pragma unroll
  for (int mt = 0; mt < 4; mt++)
#pragma unroll
    for (int nt = 0; nt < 4; nt++)
#pragma unroll
      for (int r = 0; r < 4; r++) {
        int m = m0 + mt * 16 + quad * 4 + r;
        int c = c0 + nt * 16 + l15;
        out[(size_t)m * 1024 + c] = acc[mt][nt][r] + bias[c];
      }
}

extern "C" void kernel_launch(void* const* d_in, const int* in_sizes, int n_in,
                              void* d_out, int out_size, void* d_ws, size_t ws_size,
                              hipStream_t stream) {
  const float* x    = (const float*)d_in[0];
  const float* Wqkv = (const float*)d_in[1];
  const float* ab   = (const float*)d_in[2];
  // d_in[3] (bias_idxs) unused: idx == |n/32-m/32|*32 + |n%32-m%32| analytically
  const float* Wout = (const float*)d_in[4];
  const float* bout = (const float*)d_in[5];
  float* out = (float*)d_out;

  char* ws = (char*)d_ws;
  unsigned short* xb  = (unsigned short*)(ws);                    // 16 MB
  unsigned short* wqb = (unsigned short*)(ws + 16777216);         // 6 MB
  unsigned short* wob = (unsigned short*)(ws + 23068672);         // 2 MB
  unsigned short* qw  = (unsigned short*)(ws + 25165824);         // 16 MB
  unsigned short* kw  = (unsigned short*)(ws + 41943040);         // 16 MB
  unsigned short* vw  = (unsigned short*)(ws + 58720256);         // 16 MB (vT)
  unsigned short* ow  = (unsigned short*)(ws + 75497472);         // 16 MB

  cast3_kernel<<<1536, 256, 0, stream>>>(x, Wqkv, Wout, xb, wqb, wob);
  gemm_qkv<<<dim3(12, 64), 256, 0, stream>>>(xb, wqb, qw, kw, vw);
  attn_kernel<<<512, 256, 0, stream>>>(qw, kw, vw, ab, ow);
  gemm_out_k<<<dim3(8, 64), 256, 0, stream>>>(ow, wob, bout, out);
}

// Round 11
// 251.677 us; speedup vs baseline: 1.0410x; 1.0410x over previous
//
#include <hip/hip_runtime.h>

typedef __attribute__((ext_vector_type(8))) short bf16x8;
typedef __attribute__((ext_vector_type(4))) short bf16x4;
typedef __attribute__((ext_vector_type(4))) float f32x4;

#define L2E 1.44269504088896340736f
#define QSCL 0.18033688011112042f   // 0.125 * log2(e)

__device__ inline unsigned short f2bf(float f) {
  union { float f; unsigned int u; } x; x.f = f;
  return (unsigned short)((x.u + 0x8000u) >> 16);
}
__device__ inline unsigned int f2bf2(float a, float b) {
  union { float f; unsigned int u; } xa, xb;
  xa.f = a; xb.f = b;
  return ((xa.u + 0x8000u) >> 16) | (((xb.u + 0x8000u) & 0xFFFF0000u));
}
// HW packed f32->bf16x2 (gfx950 v_cvt_pk_bf16_f32), compile-safe fallback.
__device__ inline unsigned int pk_bf16(float a, float b) {
#if __has_builtin(__builtin_amdgcn_cvt_pk_bf16_f32)
  typedef __attribute__((ext_vector_type(2))) __bf16 bfv2;
  union { bfv2 v; unsigned int u; } x;
  x.v = __builtin_amdgcn_cvt_pk_bf16_f32(a, b);
  return x.u;
#else
  return f2bf2(a, b);
#endif
}

__device__ inline void gl_lds16(const void* g, void* l) {
  __builtin_amdgcn_global_load_lds((const __attribute__((address_space(1))) void*)g,
                                   (__attribute__((address_space(3))) void*)l,
                                   16, 0, 0);
}

// Full drain (attn): compiler emits NO vmcnt before s_barrier here (R4 race
// proved it) — so the wait is entirely ours to specify.
__device__ inline void vm_drain() {
  asm volatile("s_waitcnt vmcnt(0)" ::: "memory");
}
// Partial drain (GEMM 3-stage pipeline): wave has <=8 gl_lds outstanding
// (tiles i, i+1, 4 instr each); waiting to 4 retires exactly tile i's DMA
// while tile i+1 stays in flight across the barrier — the AITER-style
// "never vmcnt(0)" K-loop the m97 2-buffer structure couldn't express.
__device__ inline void vm_wait4() {
  asm volatile("s_waitcnt vmcnt(4)" ::: "memory");
}

// ---------------- fused cast fp32 -> bf16 (x, W_qkv, W_out) ----------------
#define N4_X  2097152   // 8192*1024/4
#define N4_WQ 786432    // 3072*1024/4
#define N4_WO 262144    // 1024*1024/4
__global__ void cast3_kernel(const float* __restrict__ x,
                             const float* __restrict__ wq,
                             const float* __restrict__ wo,
                             unsigned short* __restrict__ xb,
                             unsigned short* __restrict__ wqb,
                             unsigned short* __restrict__ wob) {
  int i = blockIdx.x * blockDim.x + threadIdx.x;
  int st = gridDim.x * blockDim.x;
  for (; i < N4_X + N4_WQ + N4_WO; i += st) {
    const float* src; unsigned short* dst; int j;
    if (i < N4_X)            { src = x;  dst = xb;  j = i; }
    else if (i < N4_X + N4_WQ){ src = wq; dst = wqb; j = i - N4_X; }
    else                     { src = wo; dst = wob; j = i - N4_X - N4_WQ; }
    float4 v = reinterpret_cast<const float4*>(src)[j];
    ushort4 o;
    o.x = f2bf(v.x); o.y = f2bf(v.y); o.z = f2bf(v.z); o.w = f2bf(v.w);
    reinterpret_cast<ushort4*>(dst)[j] = o;
  }
}

// ---------------- QKV GEMM: [8192,1024] x [3072,1024]^T ----------------
// R11: 3-stage LDS pipeline (48 KB -> 3 blocks/CU; 1536 blocks = exactly 2
// balanced passes). Prefetch distance 2; vmcnt(4) partial wait before the
// barrier so prefetches stay in flight (vmcnt(0) every iter was the ~2.6x
// latency stall: per-pipe floor is ~31 us, measured 80.5).
// Compile-time MODE bodies (R6: runtime branch in the MFMA loop spills acc).
// MODE 0: q/k, swapped-operand MFMA -> C^T -> b64 stores to [b,h,n,64].
// MODE 1: v, normal MFMA -> b64 stores to vT [b,h,64,n].
template <int MODE>
__device__ __forceinline__ void gemm_qkv_body(
    unsigned short* __restrict__ sA,   // [3][128*32] flattened
    unsigned short* __restrict__ sB,
    const unsigned short* __restrict__ A,
    const unsigned short* __restrict__ Bm,
    unsigned short* __restrict__ qo,
    unsigned short* __restrict__ ko,
    unsigned short* __restrict__ vo) {
  const int K = 1024;
  const int tid = threadIdx.x;
  const int w = tid >> 6, lane = tid & 63;
  const int l15 = lane & 15, quad = lane >> 4;
  const int wm = (w >> 1) * 64, wn = (w & 1) * 64;
  const int tm = blockIdx.y, tn = blockIdx.x;

  const unsigned short* Ab = A + (size_t)(tm * 128) * K;
  const unsigned short* Bb = Bm + (size_t)(tn * 128) * K;

  const int srow = w * 32 + (lane >> 2);
  const int scol = (((lane & 3) ^ ((lane >> 3) & 3))) * 8;   // swizzled content chunk
  const int rsw = (l15 >> 1) & 3;                            // read-side swizzle key

  const f32x4 fz = {0.f, 0.f, 0.f, 0.f};
  f32x4 acc[4][4];
#pragma unroll
  for (int i = 0; i < 4; i++)
#pragma unroll
    for (int j = 0; j < 4; j++) acc[i][j] = fz;

  // stage tile (k-offset kn) into buffer nb: 4 gl_lds per thread
#define QKV_STAGE(kn, nb)                                                        \
  do {                                                                           \
    gl_lds16(Ab + (size_t)srow * K + (kn) + scol,        &sA[(nb) * 4096 + (w * 32) * 32]);      \
    gl_lds16(Ab + (size_t)(srow + 16) * K + (kn) + scol, &sA[(nb) * 4096 + (w * 32 + 16) * 32]); \
    gl_lds16(Bb + (size_t)srow * K + (kn) + scol,        &sB[(nb) * 4096 + (w * 32) * 32]);      \
    gl_lds16(Bb + (size_t)(srow + 16) * K + (kn) + scol, &sB[(nb) * 4096 + (w * 32 + 16) * 32]); \
  } while (0)

  QKV_STAGE(0, 0);
  QKV_STAGE(32, 1);

  int bi = 0;
  for (int k0 = 0; k0 < K; k0 += 32) {
    if (k0 + 64 < K) vm_wait4(); else vm_drain();
    __syncthreads();
    if (k0 + 64 < K) {
      int nb = bi + 2; if (nb >= 3) nb -= 3;
      QKV_STAGE(k0 + 64, nb);
    }
    bf16x8 af[4], bfr[4];
#pragma unroll
    for (int mt = 0; mt < 4; mt++)
      af[mt] = *(const bf16x8*)&sA[bi * 4096 + (wm + mt * 16 + l15) * 32 + ((quad ^ rsw) << 3)];
#pragma unroll
    for (int nt = 0; nt < 4; nt++)
      bfr[nt] = *(const bf16x8*)&sB[bi * 4096 + (wn + nt * 16 + l15) * 32 + ((quad ^ rsw) << 3)];
#pragma unroll
    for (int mt = 0; mt < 4; mt++)
#pragma unroll
      for (int nt = 0; nt < 4; nt++) {
        if (MODE == 0)
          acc[mt][nt] = __builtin_amdgcn_mfma_f32_16x16x32_bf16(bfr[nt], af[mt], acc[mt][nt], 0, 0, 0);
        else
          acc[mt][nt] = __builtin_amdgcn_mfma_f32_16x16x32_bf16(af[mt], bfr[nt], acc[mt][nt], 0, 0, 0);
      }
    bi = bi + 1; if (bi == 3) bi = 0;
  }
#undef QKV_STAGE

  const int m0 = tm * 128;
  const int bb = m0 >> 10, n0 = m0 & 1023;
  const int cbase = (tn * 128) & 1023;

  if (MODE == 0) {
    const int which = tn >> 3;                 // 0:q 1:k
    const float scl = (which == 0) ? QSCL : 1.0f;
    unsigned short* dst = (which == 0) ? qo : ko;
#pragma unroll
    for (int mt = 0; mt < 4; mt++) {
      int tok = n0 + wm + mt * 16 + l15;
#pragma unroll
      for (int nt = 0; nt < 4; nt++) {
        int c = cbase + wn + nt * 16 + quad * 4;
        int hh = c >> 6, d0 = c & 63;
        uint2 val;
        val.x = f2bf2(acc[mt][nt][0] * scl, acc[mt][nt][1] * scl);
        val.y = f2bf2(acc[mt][nt][2] * scl, acc[mt][nt][3] * scl);
        *(uint2*)&dst[(((size_t)bb * 16 + hh) * 1024 + tok) * 64 + d0] = val;
      }
    }
  } else {
#pragma unroll
    for (int mt = 0; mt < 4; mt++) {
      int tok = n0 + wm + mt * 16 + quad * 4;
#pragma unroll
      for (int nt = 0; nt < 4; nt++) {
        int c = cbase + wn + nt * 16 + l15;
        int hh = c >> 6, dd = c & 63;
        uint2 val;
        val.x = f2bf2(acc[mt][nt][0], acc[mt][nt][1]);
        val.y = f2bf2(acc[mt][nt][2], acc[mt][nt][3]);
        *(uint2*)&vo[(((size_t)bb * 16 + hh) * 64 + dd) * 1024 + tok] = val;
      }
    }
  }
}

__global__ __launch_bounds__(256, 3) void gemm_qkv(
    const unsigned short* __restrict__ A,
    const unsigned short* __restrict__ Bm,
    unsigned short* __restrict__ qo,
    unsigned short* __restrict__ ko,
    unsigned short* __restrict__ vo) {
  __shared__ unsigned short sA[3][128 * 32];
  __shared__ unsigned short sB[3][128 * 32];
  if (blockIdx.x < 16) gemm_qkv_body<0>(&sA[0][0], &sB[0][0], A, Bm, qo, ko, vo);
  else                 gemm_qkv_body<1>(&sA[0][0], &sB[0][0], A, Bm, qo, ko, vo);
}

// ---------------- flash attention: S^T, register PV, reflected-bias, MFMA rsum ----
// qb=4: each wave covers 64 q-rows (block 256, grid 512). K/V LDS fragment
// reads are qb-independent -> per-CU K/V LDS traffic halves vs qb=2.
// Bias row index stays wave-uniform per qb: qi = qt*8 + w*2 + (qb>>1).
__global__ __launch_bounds__(256, 2) void attn_kernel(
    const unsigned short* __restrict__ Q,
    const unsigned short* __restrict__ Kg,
    const unsigned short* __restrict__ Vt,
    const float* __restrict__ biases,
    unsigned short* __restrict__ Og) {
  __shared__ unsigned short sK[2][64 * 64];
  __shared__ unsigned short sV[2][64 * 64];   // [d][kv], 16B-chunk XOR-swizzled
  __shared__ float sBias2[32 * 63];           // reflected: [di][31 + (qj-kvj)]

  const int bx = blockIdx.x;
  const int bh = bx & 127, qt = bx >> 7;      // qt 0..3; same bh -> same XCD
  const int h = bh & 15, b = bh >> 4;
  const int tid = threadIdx.x, w = tid >> 6, lane = tid & 63;
  const int l15 = lane & 15, quad = lane >> 4;

  const size_t bhs = (size_t)(b * 16 + h);
  const unsigned short* qbase = Q + (bhs * 1024 + (size_t)qt * 256) * 64;
  const unsigned short* kbase = Kg + bhs * 1024 * 64;
  const unsigned short* vbase = Vt + bhs * 64 * 1024;

  for (int t = tid; t < 2048; t += 256) {
    int d = t >> 6, u = t & 63;
    if (u < 63) {
      int dj = u - 31; dj = dj < 0 ? -dj : dj;
      sBias2[d * 63 + u] = biases[h * 1024 + d * 32 + dj] * L2E;
    }
  }

  const int sr0 = w * 16 + (lane >> 3);
  const int sc8 = lane & 7;
  const int sw0 = sc8 ^ (lane >> 3);

  gl_lds16(kbase + (size_t)sr0 * 64 + sw0 * 8,        &sK[0][(w * 16) * 64]);
  gl_lds16(kbase + (size_t)(sr0 + 8) * 64 + sw0 * 8,  &sK[0][(w * 16 + 8) * 64]);
  gl_lds16(vbase + (size_t)sr0 * 1024 + sw0 * 8,      &sV[0][(w * 16) * 64]);
  gl_lds16(vbase + (size_t)(sr0 + 8) * 1024 + sw0 * 8,&sV[0][(w * 16 + 8) * 64]);

  bf16x8 qf[4][2];
#pragma unroll
  for (int qb = 0; qb < 4; qb++)
#pragma unroll
    for (int kd = 0; kd < 2; kd++)
      qf[qb][kd] = *(const bf16x8*)(qbase + (w * 64 + qb * 16 + l15) * 64 + kd * 32 + quad * 8);

  const int qg0 = qt * 256 + w * 64;
  const int qtw = __builtin_amdgcn_readfirstlane(qt * 8 + w * 2);
  // signed column offset (table is reflected): depends only on (qb&1, kp)
  int cc2[2][2];
#pragma unroll
  for (int qh = 0; qh < 2; qh++)
#pragma unroll
    for (int kp = 0; kp < 2; kp++)
      cc2[qh][kp] = qh * 16 + l15 - kp * 16 - quad * 4;

  const f32x4 fz = {0.f, 0.f, 0.f, 0.f};
  f32x4 of[4][4], osum[4];
#pragma unroll
  for (int i = 0; i < 4; i++) {
    osum[i] = fz;
#pragma unroll
    for (int j = 0; j < 4; j++) of[i][j] = fz;
  }
  const bf16x4 vones = {(short)0x3F80, (short)0x3F80, (short)0x3F80, (short)0x3F80};

  int buf = 0;
  for (int j0 = 0; j0 < 1024; j0 += 64) {
    vm_drain();
    __syncthreads();
    if (j0 + 64 < 1024) {
      int nb = buf ^ 1, jn = j0 + 64;
      gl_lds16(kbase + (size_t)(jn + sr0) * 64 + sw0 * 8,       &sK[nb][(w * 16) * 64]);
      gl_lds16(kbase + (size_t)(jn + sr0 + 8) * 64 + sw0 * 8,   &sK[nb][(w * 16 + 8) * 64]);
      gl_lds16(vbase + (size_t)sr0 * 1024 + jn + sw0 * 8,       &sV[nb][(w * 16) * 64]);
      gl_lds16(vbase + (size_t)(sr0 + 8) * 1024 + jn + sw0 * 8, &sV[nb][(w * 16 + 8) * 64]);
    }
    const unsigned short* K_ = sK[buf];
    const unsigned short* V_ = sV[buf];
    const int j5 = j0 >> 5;
    const int dh = qtw - j5;                  // qi(qb) = qtw + (qb>>1)
    const float* b0 = sBias2 + abs(dh) * 63 + 31;       // (qb>>1) == (kvb>>1)
    const float* bM = sBias2 + abs(dh - 1) * 63 + 31;   // qb<2, kvb>=2
    const float* bP = sBias2 + abs(dh + 1) * 63 + 31;   // qb>=2, kvb<2

#pragma unroll
    for (int kvb = 0; kvb < 4; kvb++) {
      bf16x8 kf0 = *(const bf16x8*)&K_[(kvb * 16 + l15) * 64 + ((quad ^ (l15 & 7)) << 3)];
      bf16x8 kf1 = *(const bf16x8*)&K_[(kvb * 16 + l15) * 64 + (((4 + quad) ^ (l15 & 7)) << 3)];
      bf16x4 vf[4];
#pragma unroll
      for (int nt = 0; nt < 4; nt++) {
        int d = nt * 16 + l15;
        vf[nt] = *(const bf16x4*)&V_[d * 64 + (((kvb * 2 + (quad >> 1)) ^ (l15 & 7)) << 3) + (quad & 1) * 4];
      }
      const int kp = kvb & 1;
#pragma unroll
      for (int qb = 0; qb < 4; qb++) {
        f32x4 s4 = __builtin_amdgcn_mfma_f32_16x16x32_bf16(kf0, qf[qb][0], fz, 0, 0, 0);
        s4 = __builtin_amdgcn_mfma_f32_16x16x32_bf16(kf1, qf[qb][1], s4, 0, 0, 0);
        const float* bp = (qb < 2) ? ((kvb < 2) ? b0 : bM)
                                   : ((kvb < 2) ? bP : b0);
        const float* bq = bp + cc2[qb & 1][kp];   // bq[-r] = bias for kv=kvjb+r
        float p0 = __builtin_amdgcn_exp2f(s4.x + bq[0]);
        float p1 = __builtin_amdgcn_exp2f(s4.y + bq[-1]);
        float p2 = __builtin_amdgcn_exp2f(s4.z + bq[-2]);
        float p3 = __builtin_amdgcn_exp2f(s4.w + bq[-3]);
        union { unsigned int u[2]; bf16x4 v; } pk;
        pk.u[0] = pk_bf16(p0, p1);
        pk.u[1] = pk_bf16(p2, p3);
#pragma unroll
        for (int nt = 0; nt < 4; nt++)
          of[qb][nt] = __builtin_amdgcn_mfma_f32_16x16x16bf16_1k(pk.v, vf[nt], of[qb][nt], 0, 0, 0);
        osum[qb] = __builtin_amdgcn_mfma_f32_16x16x16bf16_1k(pk.v, vones, osum[qb], 0, 0, 0);
      }
    }
    buf ^= 1;
  }

  const int kvq = quad * 4;
#pragma unroll
  for (int qb = 0; qb < 4; qb++)
#pragma unroll
    for (int r = 0; r < 4; r++) {
      float inv = __builtin_amdgcn_rcpf(osum[qb][r]);   // same C-layout row as of
      int n = qg0 + qb * 16 + kvq + r;
      size_t orow = ((size_t)b * 1024 + n) * 1024 + h * 64;
#pragma unroll
      for (int nt = 0; nt < 4; nt++)
        Og[orow + nt * 16 + l15] = f2bf(of[qb][nt][r] * inv);
    }
}

// ---------------- out-proj GEMM: [8192,1024] x [1024,1024]^T + b ----------------
// Same 3-stage vmcnt(4) pipeline as gemm_qkv.
__global__ __launch_bounds__(256, 3) void gemm_out_k(
    const unsigned short* __restrict__ A,
    const unsigned short* __restrict__ Bm,
    const float* __restrict__ bias,
    float* __restrict__ out) {
  __shared__ unsigned short sA[3][128 * 32];
  __shared__ unsigned short sB[3][128 * 32];
  const int K = 1024;
  const int tid = threadIdx.x;
  const int w = tid >> 6, lane = tid & 63;
  const int l15 = lane & 15, quad = lane >> 4;
  const int wm = (w >> 1) * 64, wn = (w & 1) * 64;
  const int tm = blockIdx.y, tn = blockIdx.x;

  const unsigned short* Ab = A + (size_t)(tm * 128) * K;
  const unsigned short* Bb = Bm + (size_t)(tn * 128) * K;

  const int srow = w * 32 + (lane >> 2);
  const int scol = (((lane & 3) ^ ((lane >> 3) & 3))) * 8;
  const int rsw = (l15 >> 1) & 3;

  const f32x4 fz = {0.f, 0.f, 0.f, 0.f};
  f32x4 acc[4][4];
#pragma unroll
  for (int i = 0; i < 4; i++)
#pragma unroll
    for (int j = 0; j < 4; j++) acc[i][j] = fz;

#define OUT_STAGE(kn, nb)                                                        \
  do {                                                                           \
    gl_lds16(Ab + (size_t)srow * K + (kn) + scol,        &sA[nb][(w * 32) * 32]);      \
    gl_lds16(Ab + (size_t)(srow + 16) * K + (kn) + scol, &sA[nb][(w * 32 + 16) * 32]); \
    gl_lds16(Bb + (size_t)srow * K + (kn) + scol,        &sB[nb][(w * 32) * 32]);      \
    gl_lds16(Bb + (size_t)(srow + 16) * K + (kn) + scol, &sB[nb][(w * 32 + 16) * 32]); \
  } while (0)

  OUT_STAGE(0, 0);
  OUT_STAGE(32, 1);

  int bi = 0;
  for (int k0 = 0; k0 < K; k0 += 32) {
    if (k0 + 64 < K) vm_wait4(); else vm_drain();
    __syncthreads();
    if (k0 + 64 < K) {
      int nb = bi + 2; if (nb >= 3) nb -= 3;
      OUT_STAGE(k0 + 64, nb);
    }
    bf16x8 af[4], bfr[4];
#pragma unroll
    for (int mt = 0; mt < 4; mt++)
      af[mt] = *(const bf16x8*)&sA[bi][(wm + mt * 16 + l15) * 32 + ((quad ^ rsw) << 3)];
#pragma unroll
    for (int nt = 0; nt < 4; nt++)
      bfr[nt] = *(const bf16x8*)&sB[bi][(wn + nt * 16 + l15) * 32 + ((quad ^ rsw) << 3)];
#pragma unroll
    for (int mt = 0; mt < 4; mt++)
#pragma unroll
      for (int nt = 0; nt < 4; nt++)
        acc[mt][nt] = __builtin_amdgcn_mfma_f32_16x16x32_bf16(af[mt], bfr[nt], acc[mt][nt], 0, 0, 0);
    bi = bi + 1; if (bi == 3) bi = 0;
  }
#undef OUT_STAGE

  const int m0 = tm * 128 + wm, c0 = tn * 128 + wn;
#pragma unroll
  for (int mt = 0; mt < 4; mt++)
#pragma unroll
    for (int nt = 0; nt < 4; nt++)
#pragma unroll
      for (int r = 0; r < 4; r++) {
        int m = m0 + mt * 16 + quad * 4 + r;
        int c = c0 + nt * 16 + l15;
        out[(size_t)m * 1024 + c] = acc[mt][nt][r] + bias[c];
      }
}

extern "C" void kernel_launch(void* const* d_in, const int* in_sizes, int n_in,
                              void* d_out, int out_size, void* d_ws, size_t ws_size,
                              hipStream_t stream) {
  const float* x    = (const float*)d_in[0];
  const float* Wqkv = (const float*)d_in[1];
  const float* ab   = (const float*)d_in[2];
  // d_in[3] (bias_idxs) unused: idx == |n/32-m/32|*32 + |n%32-m%32| analytically
  const float* Wout = (const float*)d_in[4];
  const float* bout = (const float*)d_in[5];
  float* out = (float*)d_out;

  char* ws = (char*)d_ws;
  unsigned short* xb  = (unsigned short*)(ws);                    // 16 MB
  unsigned short* wqb = (unsigned short*)(ws + 16777216);         // 6 MB
  unsigned short* wob = (unsigned short*)(ws + 23068672);         // 2 MB
  unsigned short* qw  = (unsigned short*)(ws + 25165824);         // 16 MB
  unsigned short* kw  = (unsigned short*)(ws + 41943040);         // 16 MB
  unsigned short* vw  = (unsigned short*)(ws + 58720256);         // 16 MB (vT)
  unsigned short* ow  = (unsigned short*)(ws + 75497472);         // 16 MB

  cast3_kernel<<<1536, 256, 0, stream>>>(x, Wqkv, Wout, xb, wqb, wob);
  gemm_qkv<<<dim3(24, 64), 256, 0, stream>>>(xb, wqb, qw, kw, vw);
  attn_kernel<<<512, 256, 0, stream>>>(qw, kw, vw, ab, ow);
  gemm_out_k<<<dim3(8, 64), 256, 0, stream>>>(ow, wob, bout, out);
}

// Round 12
// 250.841 us; speedup vs baseline: 1.0444x; 1.0033x over previous
//
#include <hip/hip_runtime.h>

typedef __attribute__((ext_vector_type(8))) short bf16x8;
typedef __attribute__((ext_vector_type(4))) short bf16x4;
typedef __attribute__((ext_vector_type(4))) float f32x4;

#define L2E 1.44269504088896340736f
#define QSCL 0.18033688011112042f   // 0.125 * log2(e)

__device__ inline unsigned short f2bf(float f) {
  union { float f; unsigned int u; } x; x.f = f;
  return (unsigned short)((x.u + 0x8000u) >> 16);
}
__device__ inline unsigned int f2bf2(float a, float b) {
  union { float f; unsigned int u; } xa, xb;
  xa.f = a; xb.f = b;
  return ((xa.u + 0x8000u) >> 16) | (((xb.u + 0x8000u) & 0xFFFF0000u));
}
// HW packed f32->bf16x2 (gfx950 v_cvt_pk_bf16_f32), compile-safe fallback.
__device__ inline unsigned int pk_bf16(float a, float b) {
#if __has_builtin(__builtin_amdgcn_cvt_pk_bf16_f32)
  typedef __attribute__((ext_vector_type(2))) __bf16 bfv2;
  union { bfv2 v; unsigned int u; } x;
  x.v = __builtin_amdgcn_cvt_pk_bf16_f32(a, b);
  return x.u;
#else
  return f2bf2(a, b);
#endif
}

__device__ inline void gl_lds16(const void* g, void* l) {
  __builtin_amdgcn_global_load_lds((const __attribute__((address_space(1))) void*)g,
                                   (__attribute__((address_space(3))) void*)l,
                                   16, 0, 0);
}

// Full drain (attn): compiler emits NO vmcnt before s_barrier here (R4 race
// proved it) — so the wait is entirely ours to specify.
__device__ inline void vm_drain() {
  asm volatile("s_waitcnt vmcnt(0)" ::: "memory");
}
// Partial drains for the 3-stage GEMM pipelines (placed BEFORE staging i+2):
// outstanding = tiles i, i+1; draining to (loads/tile) retires exactly tile i
// while tile i+1 stays in flight across the barrier.
__device__ inline void vm_wait4() {   // gemm_qkv: 4 gl_lds per tile
  asm volatile("s_waitcnt vmcnt(4)" ::: "memory");
}
__device__ inline void vm_wait3() {   // gemm_out: 3 gl_lds per tile
  asm volatile("s_waitcnt vmcnt(3)" ::: "memory");
}

// ---------------- fused cast fp32 -> bf16 (x, W_qkv, W_out) ----------------
#define N4_X  2097152   // 8192*1024/4
#define N4_WQ 786432    // 3072*1024/4
#define N4_WO 262144    // 1024*1024/4
__global__ void cast3_kernel(const float* __restrict__ x,
                             const float* __restrict__ wq,
                             const float* __restrict__ wo,
                             unsigned short* __restrict__ xb,
                             unsigned short* __restrict__ wqb,
                             unsigned short* __restrict__ wob) {
  int i = blockIdx.x * blockDim.x + threadIdx.x;
  int st = gridDim.x * blockDim.x;
  for (; i < N4_X + N4_WQ + N4_WO; i += st) {
    const float* src; unsigned short* dst; int j;
    if (i < N4_X)            { src = x;  dst = xb;  j = i; }
    else if (i < N4_X + N4_WQ){ src = wq; dst = wqb; j = i - N4_X; }
    else                     { src = wo; dst = wob; j = i - N4_X - N4_WQ; }
    float4 v = reinterpret_cast<const float4*>(src)[j];
    ushort4 o;
    o.x = f2bf(v.x); o.y = f2bf(v.y); o.z = f2bf(v.z); o.w = f2bf(v.w);
    reinterpret_cast<ushort4*>(dst)[j] = o;
  }
}

// ---------------- QKV GEMM: [8192,1024] x [3072,1024]^T ----------------
// 3-stage LDS pipeline (48 KB -> 3 blocks/CU; 1536 blocks = 2 balanced passes),
// prefetch distance 2, vmcnt(4) partial wait. At K=1024 (32 iters) this sits at
// ~670 TF — 2x the m97-ladder's small-K point (m102: N=2048 -> 320 TF); further
// gains need hipBLASLt-style wave specialization (out of scope).
// Compile-time MODE bodies (R6: runtime branch in the MFMA loop spills acc).
template <int MODE>
__device__ __forceinline__ void gemm_qkv_body(
    unsigned short* __restrict__ sA,   // [3][128*32] flattened
    unsigned short* __restrict__ sB,
    const unsigned short* __restrict__ A,
    const unsigned short* __restrict__ Bm,
    unsigned short* __restrict__ qo,
    unsigned short* __restrict__ ko,
    unsigned short* __restrict__ vo) {
  const int K = 1024;
  const int tid = threadIdx.x;
  const int w = tid >> 6, lane = tid & 63;
  const int l15 = lane & 15, quad = lane >> 4;
  const int wm = (w >> 1) * 64, wn = (w & 1) * 64;
  const int tm = blockIdx.y, tn = blockIdx.x;

  const unsigned short* Ab = A + (size_t)(tm * 128) * K;
  const unsigned short* Bb = Bm + (size_t)(tn * 128) * K;

  const int srow = w * 32 + (lane >> 2);
  const int scol = (((lane & 3) ^ ((lane >> 3) & 3))) * 8;   // swizzled content chunk
  const int rsw = (l15 >> 1) & 3;                            // read-side swizzle key

  const f32x4 fz = {0.f, 0.f, 0.f, 0.f};
  f32x4 acc[4][4];
#pragma unroll
  for (int i = 0; i < 4; i++)
#pragma unroll
    for (int j = 0; j < 4; j++) acc[i][j] = fz;

#define QKV_STAGE(kn, nb)                                                        \
  do {                                                                           \
    gl_lds16(Ab + (size_t)srow * K + (kn) + scol,        &sA[(nb) * 4096 + (w * 32) * 32]);      \
    gl_lds16(Ab + (size_t)(srow + 16) * K + (kn) + scol, &sA[(nb) * 4096 + (w * 32 + 16) * 32]); \
    gl_lds16(Bb + (size_t)srow * K + (kn) + scol,        &sB[(nb) * 4096 + (w * 32) * 32]);      \
    gl_lds16(Bb + (size_t)(srow + 16) * K + (kn) + scol, &sB[(nb) * 4096 + (w * 32 + 16) * 32]); \
  } while (0)

  QKV_STAGE(0, 0);
  QKV_STAGE(32, 1);

  int bi = 0;
  for (int k0 = 0; k0 < K; k0 += 32) {
    if (k0 + 64 < K) vm_wait4(); else vm_drain();
    __syncthreads();
    if (k0 + 64 < K) {
      int nb = bi + 2; if (nb >= 3) nb -= 3;
      QKV_STAGE(k0 + 64, nb);
    }
    bf16x8 af[4], bfr[4];
#pragma unroll
    for (int mt = 0; mt < 4; mt++)
      af[mt] = *(const bf16x8*)&sA[bi * 4096 + (wm + mt * 16 + l15) * 32 + ((quad ^ rsw) << 3)];
#pragma unroll
    for (int nt = 0; nt < 4; nt++)
      bfr[nt] = *(const bf16x8*)&sB[bi * 4096 + (wn + nt * 16 + l15) * 32 + ((quad ^ rsw) << 3)];
#pragma unroll
    for (int mt = 0; mt < 4; mt++)
#pragma unroll
      for (int nt = 0; nt < 4; nt++) {
        if (MODE == 0)
          acc[mt][nt] = __builtin_amdgcn_mfma_f32_16x16x32_bf16(bfr[nt], af[mt], acc[mt][nt], 0, 0, 0);
        else
          acc[mt][nt] = __builtin_amdgcn_mfma_f32_16x16x32_bf16(af[mt], bfr[nt], acc[mt][nt], 0, 0, 0);
      }
    bi = bi + 1; if (bi == 3) bi = 0;
  }
#undef QKV_STAGE

  const int m0 = tm * 128;
  const int bb = m0 >> 10, n0 = m0 & 1023;
  const int cbase = (tn * 128) & 1023;

  if (MODE == 0) {
    const int which = tn >> 3;                 // 0:q 1:k
    const float scl = (which == 0) ? QSCL : 1.0f;
    unsigned short* dst = (which == 0) ? qo : ko;
#pragma unroll
    for (int mt = 0; mt < 4; mt++) {
      int tok = n0 + wm + mt * 16 + l15;
#pragma unroll
      for (int nt = 0; nt < 4; nt++) {
        int c = cbase + wn + nt * 16 + quad * 4;
        int hh = c >> 6, d0 = c & 63;
        uint2 val;
        val.x = f2bf2(acc[mt][nt][0] * scl, acc[mt][nt][1] * scl);
        val.y = f2bf2(acc[mt][nt][2] * scl, acc[mt][nt][3] * scl);
        *(uint2*)&dst[(((size_t)bb * 16 + hh) * 1024 + tok) * 64 + d0] = val;
      }
    }
  } else {
#pragma unroll
    for (int mt = 0; mt < 4; mt++) {
      int tok = n0 + wm + mt * 16 + quad * 4;
#pragma unroll
      for (int nt = 0; nt < 4; nt++) {
        int c = cbase + wn + nt * 16 + l15;
        int hh = c >> 6, dd = c & 63;
        uint2 val;
        val.x = f2bf2(acc[mt][nt][0], acc[mt][nt][1]);
        val.y = f2bf2(acc[mt][nt][2], acc[mt][nt][3]);
        *(uint2*)&vo[(((size_t)bb * 16 + hh) * 64 + dd) * 1024 + tok] = val;
      }
    }
  }
}

__global__ __launch_bounds__(256, 3) void gemm_qkv(
    const unsigned short* __restrict__ A,
    const unsigned short* __restrict__ Bm,
    unsigned short* __restrict__ qo,
    unsigned short* __restrict__ ko,
    unsigned short* __restrict__ vo) {
  __shared__ unsigned short sA[3][128 * 32];
  __shared__ unsigned short sB[3][128 * 32];
  if (blockIdx.x < 16) gemm_qkv_body<0>(&sA[0][0], &sB[0][0], A, Bm, qo, ko, vo);
  else                 gemm_qkv_body<1>(&sA[0][0], &sB[0][0], A, Bm, qo, ko, vo);
}

// ---------------- flash attention: S^T, register PV, reflected-bias, MFMA rsum ----
__global__ __launch_bounds__(256, 2) void attn_kernel(
    const unsigned short* __restrict__ Q,
    const unsigned short* __restrict__ Kg,
    const unsigned short* __restrict__ Vt,
    const float* __restrict__ biases,
    unsigned short* __restrict__ Og) {
  __shared__ unsigned short sK[2][64 * 64];
  __shared__ unsigned short sV[2][64 * 64];   // [d][kv], 16B-chunk XOR-swizzled
  __shared__ float sBias2[32 * 63];           // reflected: [di][31 + (qj-kvj)]

  const int bx = blockIdx.x;
  const int bh = bx & 127, qt = bx >> 7;      // qt 0..3; same bh -> same XCD
  const int h = bh & 15, b = bh >> 4;
  const int tid = threadIdx.x, w = tid >> 6, lane = tid & 63;
  const int l15 = lane & 15, quad = lane >> 4;

  const size_t bhs = (size_t)(b * 16 + h);
  const unsigned short* qbase = Q + (bhs * 1024 + (size_t)qt * 256) * 64;
  const unsigned short* kbase = Kg + bhs * 1024 * 64;
  const unsigned short* vbase = Vt + bhs * 64 * 1024;

  for (int t = tid; t < 2048; t += 256) {
    int d = t >> 6, u = t & 63;
    if (u < 63) {
      int dj = u - 31; dj = dj < 0 ? -dj : dj;
      sBias2[d * 63 + u] = biases[h * 1024 + d * 32 + dj] * L2E;
    }
  }

  const int sr0 = w * 16 + (lane >> 3);
  const int sc8 = lane & 7;
  const int sw0 = sc8 ^ (lane >> 3);

  gl_lds16(kbase + (size_t)sr0 * 64 + sw0 * 8,        &sK[0][(w * 16) * 64]);
  gl_lds16(kbase + (size_t)(sr0 + 8) * 64 + sw0 * 8,  &sK[0][(w * 16 + 8) * 64]);
  gl_lds16(vbase + (size_t)sr0 * 1024 + sw0 * 8,      &sV[0][(w * 16) * 64]);
  gl_lds16(vbase + (size_t)(sr0 + 8) * 1024 + sw0 * 8,&sV[0][(w * 16 + 8) * 64]);

  bf16x8 qf[4][2];
#pragma unroll
  for (int qb = 0; qb < 4; qb++)
#pragma unroll
    for (int kd = 0; kd < 2; kd++)
      qf[qb][kd] = *(const bf16x8*)(qbase + (w * 64 + qb * 16 + l15) * 64 + kd * 32 + quad * 8);

  const int qg0 = qt * 256 + w * 64;
  const int qtw = __builtin_amdgcn_readfirstlane(qt * 8 + w * 2);
  int cc2[2][2];
#pragma unroll
  for (int qh = 0; qh < 2; qh++)
#pragma unroll
    for (int kp = 0; kp < 2; kp++)
      cc2[qh][kp] = qh * 16 + l15 - kp * 16 - quad * 4;

  const f32x4 fz = {0.f, 0.f, 0.f, 0.f};
  f32x4 of[4][4], osum[4];
#pragma unroll
  for (int i = 0; i < 4; i++) {
    osum[i] = fz;
#pragma unroll
    for (int j = 0; j < 4; j++) of[i][j] = fz;
  }
  const bf16x4 vones = {(short)0x3F80, (short)0x3F80, (short)0x3F80, (short)0x3F80};

  int buf = 0;
  for (int j0 = 0; j0 < 1024; j0 += 64) {
    vm_drain();
    __syncthreads();
    if (j0 + 64 < 1024) {
      int nb = buf ^ 1, jn = j0 + 64;
      gl_lds16(kbase + (size_t)(jn + sr0) * 64 + sw0 * 8,       &sK[nb][(w * 16) * 64]);
      gl_lds16(kbase + (size_t)(jn + sr0 + 8) * 64 + sw0 * 8,   &sK[nb][(w * 16 + 8) * 64]);
      gl_lds16(vbase + (size_t)sr0 * 1024 + jn + sw0 * 8,       &sV[nb][(w * 16) * 64]);
      gl_lds16(vbase + (size_t)(sr0 + 8) * 1024 + jn + sw0 * 8, &sV[nb][(w * 16 + 8) * 64]);
    }
    const unsigned short* K_ = sK[buf];
    const unsigned short* V_ = sV[buf];
    const int j5 = j0 >> 5;
    const int dh = qtw - j5;                  // qi(qb) = qtw + (qb>>1)
    const float* b0 = sBias2 + abs(dh) * 63 + 31;       // (qb>>1) == (kvb>>1)
    const float* bM = sBias2 + abs(dh - 1) * 63 + 31;   // qb<2, kvb>=2
    const float* bP = sBias2 + abs(dh + 1) * 63 + 31;   // qb>=2, kvb<2

#pragma unroll
    for (int kvb = 0; kvb < 4; kvb++) {
      bf16x8 kf0 = *(const bf16x8*)&K_[(kvb * 16 + l15) * 64 + ((quad ^ (l15 & 7)) << 3)];
      bf16x8 kf1 = *(const bf16x8*)&K_[(kvb * 16 + l15) * 64 + (((4 + quad) ^ (l15 & 7)) << 3)];
      bf16x4 vf[4];
#pragma unroll
      for (int nt = 0; nt < 4; nt++) {
        int d = nt * 16 + l15;
        vf[nt] = *(const bf16x4*)&V_[d * 64 + (((kvb * 2 + (quad >> 1)) ^ (l15 & 7)) << 3) + (quad & 1) * 4];
      }
      const int kp = kvb & 1;
#pragma unroll
      for (int qb = 0; qb < 4; qb++) {
        f32x4 s4 = __builtin_amdgcn_mfma_f32_16x16x32_bf16(kf0, qf[qb][0], fz, 0, 0, 0);
        s4 = __builtin_amdgcn_mfma_f32_16x16x32_bf16(kf1, qf[qb][1], s4, 0, 0, 0);
        const float* bp = (qb < 2) ? ((kvb < 2) ? b0 : bM)
                                   : ((kvb < 2) ? bP : b0);
        const float* bq = bp + cc2[qb & 1][kp];   // bq[-r] = bias for kv=kvjb+r
        float p0 = __builtin_amdgcn_exp2f(s4.x + bq[0]);
        float p1 = __builtin_amdgcn_exp2f(s4.y + bq[-1]);
        float p2 = __builtin_amdgcn_exp2f(s4.z + bq[-2]);
        float p3 = __builtin_amdgcn_exp2f(s4.w + bq[-3]);
        union { unsigned int u[2]; bf16x4 v; } pk;
        pk.u[0] = pk_bf16(p0, p1);
        pk.u[1] = pk_bf16(p2, p3);
#pragma unroll
        for (int nt = 0; nt < 4; nt++)
          of[qb][nt] = __builtin_amdgcn_mfma_f32_16x16x16bf16_1k(pk.v, vf[nt], of[qb][nt], 0, 0, 0);
        osum[qb] = __builtin_amdgcn_mfma_f32_16x16x16bf16_1k(pk.v, vones, osum[qb], 0, 0, 0);
      }
    }
    buf ^= 1;
  }

  const int kvq = quad * 4;
#pragma unroll
  for (int qb = 0; qb < 4; qb++)
#pragma unroll
    for (int r = 0; r < 4; r++) {
      float inv = __builtin_amdgcn_rcpf(osum[qb][r]);   // same C-layout row as of
      int n = qg0 + qb * 16 + kvq + r;
      size_t orow = ((size_t)b * 1024 + n) * 1024 + h * 64;
#pragma unroll
      for (int nt = 0; nt < 4; nt++)
        Og[orow + nt * 16 + l15] = f2bf(of[qb][nt][r] * inv);
    }
}

// ---------------- out-proj GEMM: [8192,1024] x [1024,1024]^T + b ----------------
// R12: 128x64 tiles -> grid 16x64 = 1024 blocks = exactly 4/CU single balanced
// pass (the 128x128 grid was 512 blocks = 2/CU, grid-limited occupancy).
// LDS 36 KB = 3 stages x (8K A + 4K B); 3 gl_lds/tile -> vmcnt(3) partial wait.
__global__ __launch_bounds__(256, 4) void gemm_out_k(
    const unsigned short* __restrict__ A,
    const unsigned short* __restrict__ Bm,
    const float* __restrict__ bias,
    float* __restrict__ out) {
  __shared__ unsigned short sA[3][128 * 32];
  __shared__ unsigned short sB[3][64 * 32];
  const int K = 1024;
  const int tid = threadIdx.x;
  const int w = tid >> 6, lane = tid & 63;
  const int l15 = lane & 15, quad = lane >> 4;
  const int tm = blockIdx.y, tn = blockIdx.x;

  const unsigned short* Ab = A + (size_t)(tm * 128) * K;
  const unsigned short* Bb = Bm + (size_t)(tn * 64) * K;

  const int srowA = w * 32 + (lane >> 2);
  const int srowB = w * 16 + (lane >> 2);
  const int scol = (((lane & 3) ^ ((lane >> 3) & 3))) * 8;   // swizzled content chunk
  const int rsw = (l15 >> 1) & 3;                            // read-side swizzle key

  const f32x4 fz = {0.f, 0.f, 0.f, 0.f};
  f32x4 acc[2][4];
#pragma unroll
  for (int i = 0; i < 2; i++)
#pragma unroll
    for (int j = 0; j < 4; j++) acc[i][j] = fz;

#define OUT_STAGE(kn, nb)                                                          \
  do {                                                                             \
    gl_lds16(Ab + (size_t)srowA * K + (kn) + scol,        &sA[nb][(w * 32) * 32]);      \
    gl_lds16(Ab + (size_t)(srowA + 16) * K + (kn) + scol, &sA[nb][(w * 32 + 16) * 32]); \
    gl_lds16(Bb + (size_t)srowB * K + (kn) + scol,        &sB[nb][(w * 16) * 32]);      \
  } while (0)

  OUT_STAGE(0, 0);
  OUT_STAGE(32, 1);

  int bi = 0;
  for (int k0 = 0; k0 < K; k0 += 32) {
    if (k0 + 64 < K) vm_wait3(); else vm_drain();
    __syncthreads();
    if (k0 + 64 < K) {
      int nb = bi + 2; if (nb >= 3) nb -= 3;
      OUT_STAGE(k0 + 64, nb);
    }
    bf16x8 af[2], bfr[4];
#pragma unroll
    for (int mt = 0; mt < 2; mt++)
      af[mt] = *(const bf16x8*)&sA[bi][(w * 32 + mt * 16 + l15) * 32 + ((quad ^ rsw) << 3)];
#pragma unroll
    for (int nt = 0; nt < 4; nt++)
      bfr[nt] = *(const bf16x8*)&sB[bi][(nt * 16 + l15) * 32 + ((quad ^ rsw) << 3)];
#pragma unroll
    for (int mt = 0; mt < 2; mt++)
#pragma unroll
      for (int nt = 0; nt < 4; nt++)
        acc[mt][nt] = __builtin_amdgcn_mfma_f32_16x16x32_bf16(af[mt], bfr[nt], acc[mt][nt], 0, 0, 0);
    bi = bi + 1; if (bi == 3) bi = 0;
  }
#undef OUT_STAGE

  const int m0 = tm * 128 + w * 32, c0 = tn * 64;
#pragma unroll
  for (int mt = 0; mt < 2; mt++)
#pragma unroll
    for (int nt = 0; nt < 4; nt++)
#pragma unroll
      for (int r = 0; r < 4; r++) {
        int m = m0 + mt * 16 + quad * 4 + r;
        int c = c0 + nt * 16 + l15;
        out[(size_t)m * 1024 + c] = acc[mt][nt][r] + bias[c];
      }
}

extern "C" void kernel_launch(void* const* d_in, const int* in_sizes, int n_in,
                              void* d_out, int out_size, void* d_ws, size_t ws_size,
                              hipStream_t stream) {
  const float* x    = (const float*)d_in[0];
  const float* Wqkv = (const float*)d_in[1];
  const float* ab   = (const float*)d_in[2];
  // d_in[3] (bias_idxs) unused: idx == |n/32-m/32|*32 + |n%32-m%32| analytically
  const float* Wout = (const float*)d_in[4];
  const float* bout = (const float*)d_in[5];
  float* out = (float*)d_out;

  char* ws = (char*)d_ws;
  unsigned short* xb  = (unsigned short*)(ws);                    // 16 MB
  unsigned short* wqb = (unsigned short*)(ws + 16777216);         // 6 MB
  unsigned short* wob = (unsigned short*)(ws + 23068672);         // 2 MB
  unsigned short* qw  = (unsigned short*)(ws + 25165824);         // 16 MB
  unsigned short* kw  = (unsigned short*)(ws + 41943040);         // 16 MB
  unsigned short* vw  = (unsigned short*)(ws + 58720256);         // 16 MB (vT)
  unsigned short* ow  = (unsigned short*)(ws + 75497472);         // 16 MB

  cast3_kernel<<<1536, 256, 0, stream>>>(x, Wqkv, Wout, xb, wqb, wob);
  gemm_qkv<<<dim3(24, 64), 256, 0, stream>>>(xb, wqb, qw, kw, vw);
  attn_kernel<<<512, 256, 0, stream>>>(qw, kw, vw, ab, ow);
  gemm_out_k<<<dim3(16, 64), 256, 0, stream>>>(ow, wob, bout, out);
}